// Round 2
// baseline (576.093 us; speedup 1.0000x reference)
//
#include <hip/hip_runtime.h>
#include <hip/hip_bf16.h>

typedef __bf16 bf16x8 __attribute__((ext_vector_type(8)));
typedef __bf16 bf16x4 __attribute__((ext_vector_type(4)));
typedef float  f32x4  __attribute__((ext_vector_type(4)));

#define MFMA16(a,b,c) __builtin_amdgcn_mfma_f32_16x16x32_bf16((a),(b),(c),0,0,0)

#define T_SEQ 2048
#define CDIM  1024
#define NH    16
#define DH    64
#define C3    3072

// async global->LDS, 16B per lane; LDS dest must be wave-uniform base + lane*16
#define GLDS(g, l) __builtin_amdgcn_global_load_lds( \
    (const __attribute__((address_space(1))) void*)(g), \
    (__attribute__((address_space(3))) void*)(l), 16, 0, 0)

// ---------------- cast f32 -> bf16, vectorized ----------------
__global__ void cast_f32_bf16_kernel(const float* __restrict__ in,
                                     __bf16* __restrict__ out, int n4) {
  int i = blockIdx.x * 256 + threadIdx.x;
  if (i >= n4) return;
  f32x4 v = ((const f32x4*)in)[i];
  bf16x4 o;
  o[0] = (__bf16)v[0]; o[1] = (__bf16)v[1];
  o[2] = (__bf16)v[2]; o[3] = (__bf16)v[3];
  ((bf16x4*)out)[i] = o;
}

// ---------------- transpose + cast: W[R][C] f32 -> WT[C][R] bf16 ----------------
__global__ void transpose_cast_kernel(const float* __restrict__ W,
                                      __bf16* __restrict__ WT, int R, int C) {
  __shared__ float tile[32][33];
  int c0 = blockIdx.x * 32, r0 = blockIdx.y * 32;
  int tx = threadIdx.x;   // 0..31
  int ty = threadIdx.y;   // 0..7
#pragma unroll
  for (int i = 0; i < 32; i += 8)
    tile[ty + i][tx] = W[(size_t)(r0 + ty + i) * C + c0 + tx];
  __syncthreads();
#pragma unroll
  for (int i = 0; i < 32; i += 8)
    WT[(size_t)(c0 + ty + i) * R + r0 + tx] = (__bf16)tile[tx][ty + i];
}

// ---------------- transpose V section of qkv -> VT[b][c][t] bf16 ----------------
__global__ void transpose_v_kernel(const __bf16* __restrict__ qkv,
                                   __bf16* __restrict__ VT) {
  __shared__ __bf16 tile[32][33];
  int b  = blockIdx.z;
  int t0 = blockIdx.x * 32;
  int c0 = blockIdx.y * 32;
  int tx = threadIdx.x, ty = threadIdx.y;
#pragma unroll
  for (int i = 0; i < 32; i += 8)
    tile[ty + i][tx] = qkv[(size_t)(b * T_SEQ + t0 + ty + i) * C3 + 2 * CDIM + c0 + tx];
  __syncthreads();
#pragma unroll
  for (int i = 0; i < 32; i += 8)
    VT[((size_t)b * CDIM + c0 + ty + i) * T_SEQ + t0 + tx] = tile[tx][ty + i];
}

// ---------------- bf16 GEMM: C[M][N] = A[M][K] * BT[N][K]^T ----------------
// 128x128 tile, BK=64, 256 threads (4 waves, 2x2), 16x16x32 MFMA,
// global_load_lds width-16 staging (m97 structure).
template <int STORE_BF16>
__global__ __launch_bounds__(256)
void gemm_bt_kernel(const __bf16* __restrict__ A, const __bf16* __restrict__ BT,
                    void* __restrict__ Cout, int M, int N, int K) {
  __shared__ __align__(16) __bf16 Alds[128 * 64];
  __shared__ __align__(16) __bf16 Blds[128 * 64];
  const int tid  = threadIdx.x;
  const int lane = tid & 63;
  const int g    = lane >> 4;
  const int l16  = lane & 15;
  const int wave = tid >> 6;
  const int wm   = wave >> 1, wn = wave & 1;
  const int bm   = blockIdx.x, bn = blockIdx.y;

  f32x4 acc[4][4] = {};

  // precompute per-lane staging addresses (row/col within 128x64 tile)
  const int soff = tid * 16;                // byte offset stride base
  for (int k0 = 0; k0 < K; k0 += 64) {
    __syncthreads();   // protect previous iteration's LDS reads
#pragma unroll
    for (int c = 0; c < 4; ++c) {
      int off  = c * 4096 + soff;
      int row  = off >> 7;              // 128 B per tile row (64 bf16)
      int col  = (off & 127) >> 1;
      GLDS(A  + (size_t)(bm * 128 + row) * K + k0 + col, (char*)Alds + off);
      GLDS(BT + (size_t)(bn * 128 + row) * K + k0 + col, (char*)Blds + off);
    }
    __syncthreads();   // drains vmcnt -> LDS tiles ready
#pragma unroll
    for (int kk = 0; kk < 2; ++kk) {
      bf16x8 af[4], bf_[4];
#pragma unroll
      for (int i = 0; i < 4; ++i) {
        af[i]  = *(const bf16x8*)&Alds[(wm * 64 + i * 16 + l16) * 64 + kk * 32 + g * 8];
        bf_[i] = *(const bf16x8*)&Blds[(wn * 64 + i * 16 + l16) * 64 + kk * 32 + g * 8];
      }
#pragma unroll
      for (int i = 0; i < 4; ++i)
#pragma unroll
        for (int j = 0; j < 4; ++j)
          acc[i][j] = MFMA16(af[i], bf_[j], acc[i][j]);
    }
  }

  // epilogue: D layout col=lane&15, row=(lane>>4)*4+reg
#pragma unroll
  for (int i = 0; i < 4; ++i) {
    int crow0 = bm * 128 + wm * 64 + i * 16 + g * 4;
#pragma unroll
    for (int j = 0; j < 4; ++j) {
      int ccol = bn * 128 + wn * 64 + j * 16 + l16;
#pragma unroll
      for (int r = 0; r < 4; ++r) {
        size_t idx = (size_t)(crow0 + r) * N + ccol;
        if (STORE_BF16) ((__bf16*)Cout)[idx] = (__bf16)acc[i][j][r];
        else            ((float*)Cout)[idx]  = acc[i][j][r];
      }
    }
  }
}

// ---------------- causal flash attention ----------------
// Block = (b, h, 64 q-rows). 4 waves, each wave owns 16 q rows, loops KV in
// tiles of 32. Swapped QK^T: S^T = mfma(K, Q) so lane holds P for its own q.
// V consumed via pre-transposed VT[b][c][t] -> vectorized bf16x8 A-fragments.
__global__ __launch_bounds__(256)
void attn_kernel(const __bf16* __restrict__ qkv, const __bf16* __restrict__ VT,
                 __bf16* __restrict__ y) {
  __shared__ __align__(16) __bf16 Plds[4][16][32];
  const int tid  = threadIdx.x;
  const int lane = tid & 63;
  const int g    = lane >> 4;
  const int l16  = lane & 15;
  const int wave = tid >> 6;

  const int qtile = blockIdx.x & 31;   // T/64
  const int bh    = blockIdx.x >> 5;   // 0..63
  const int h     = bh & (NH - 1);
  const int b     = bh >> 4;

  const int qg0  = qtile * 64 + wave * 16;  // first q row of this wave
  const int qrow = qg0 + l16;               // this lane's q row
  const size_t baseQ = (size_t)b * T_SEQ * C3 + (size_t)h * DH;
  const size_t baseK = baseQ + CDIM;
  const __bf16* Vt = VT + ((size_t)b * CDIM + h * DH) * T_SEQ;

  // Q fragments: Q[l16][kk*32 + g*8 + j]
  bf16x8 qf[2];
#pragma unroll
  for (int kk = 0; kk < 2; ++kk)
    qf[kk] = *(const bf16x8*)(qkv + baseQ + (size_t)qrow * C3 + kk * 32 + g * 8);

  const float NEG = -1e30f;
  const float SC  = 0.125f * 1.44269504088896340736f;  // scale * log2(e)

  float m = NEG, lsumAll = 0.f;
  f32x4 o[4] = {};

  const int ntiles = (qg0 + 15) / 32 + 1;
  for (int t = 0; t < ntiles; ++t) {
    const int kv0 = t * 32;
    // S^T tiles: two 16(kv) x 16(q) tiles
    f32x4 s[2] = {};
#pragma unroll
    for (int st = 0; st < 2; ++st) {
#pragma unroll
      for (int kk = 0; kk < 2; ++kk) {
        bf16x8 kf = *(const bf16x8*)(qkv + baseK +
                        (size_t)(kv0 + st * 16 + l16) * C3 + kk * 32 + g * 8);
        s[st] = MFMA16(kf, qf[kk], s[st]);
      }
    }
    // scale + causal mask + row max (row = q, spread over g-lane groups)
    float tv[8];
    float tmax = NEG;
#pragma unroll
    for (int st = 0; st < 2; ++st)
#pragma unroll
      for (int r = 0; r < 4; ++r) {
        int kv = kv0 + st * 16 + g * 4 + r;
        float val = (kv <= qrow) ? s[st][r] * SC : NEG;
        tv[st * 4 + r] = val;
        tmax = fmaxf(tmax, val);
      }
    tmax = fmaxf(tmax, __shfl_xor(tmax, 16));
    tmax = fmaxf(tmax, __shfl_xor(tmax, 32));
    float mnew  = fmaxf(m, tmax);
    float alpha = exp2f(m - mnew);
    lsumAll *= alpha;
#pragma unroll
    for (int d = 0; d < 4; ++d) o[d] *= alpha;

    float lsum = 0.f;
#pragma unroll
    for (int st = 0; st < 2; ++st) {
      bf16x4 pb;
#pragma unroll
      for (int r = 0; r < 4; ++r) {
        float p = exp2f(tv[st * 4 + r] - mnew);
        lsum += p;
        pb[r] = (__bf16)p;
      }
      *(bf16x4*)&Plds[wave][l16][st * 16 + g * 4] = pb;
    }
    lsum += __shfl_xor(lsum, 16);
    lsum += __shfl_xor(lsum, 32);
    lsumAll += lsum;
    m = mnew;

    // PV: O^T[d][q] += V^T[d][kv] * P^T[kv][q]
    bf16x8 pf = *(const bf16x8*)&Plds[wave][l16][g * 8];
#pragma unroll
    for (int dt = 0; dt < 4; ++dt) {
      bf16x8 vf = *(const bf16x8*)(Vt + (size_t)(dt * 16 + l16) * T_SEQ + kv0 + g * 8);
      o[dt] = MFMA16(vf, pf, o[dt]);
    }
  }

  float inv_l = 1.0f / lsumAll;
#pragma unroll
  for (int dt = 0; dt < 4; ++dt)
#pragma unroll
    for (int r = 0; r < 4; ++r) {
      int d = dt * 16 + g * 4 + r;
      y[((size_t)b * T_SEQ + qrow) * CDIM + h * DH + d] = (__bf16)(o[dt][r] * inv_l);
    }
}

// ---------------- launch ----------------
extern "C" void kernel_launch(void* const* d_in, const int* in_sizes, int n_in,
                              void* d_out, int out_size, void* d_ws, size_t ws_size,
                              hipStream_t stream) {
  const float* x      = (const float*)d_in[0];   // [4,2048,1024]
  const float* w_qkv  = (const float*)d_in[1];   // [1024,3072]
  const float* w_proj = (const float*)d_in[2];   // [1024,1024]
  float* out = (float*)d_out;                    // [4,2048,1024]

  __bf16* xb     = (__bf16*)d_ws;                // 8192*1024 (reused as VT after GEMM1)
  __bf16* wqkvT  = xb + 8388608;                 // 3072*1024
  __bf16* wprojT = wqkvT + 3145728;              // 1024*1024
  __bf16* qkv    = wprojT + 1048576;             // 8192*3072
  __bf16* yb     = qkv + 25165824;               // 8192*1024
  __bf16* VT     = xb;                           // alias: xb dead after GEMM1

  cast_f32_bf16_kernel<<<8192, 256, 0, stream>>>(x, xb, 2097152);
  transpose_cast_kernel<<<dim3(96, 32), dim3(32, 8), 0, stream>>>(w_qkv, wqkvT, 1024, 3072);
  transpose_cast_kernel<<<dim3(32, 32), dim3(32, 8), 0, stream>>>(w_proj, wprojT, 1024, 1024);
  gemm_bt_kernel<1><<<dim3(64, 24), 256, 0, stream>>>(xb, wqkvT, (void*)qkv, 8192, 3072, 1024);
  transpose_v_kernel<<<dim3(64, 32, 4), dim3(32, 8), 0, stream>>>(qkv, VT);
  attn_kernel<<<2048, 256, 0, stream>>>(qkv, VT, yb);
  gemm_bt_kernel<0><<<dim3(64, 8), 256, 0, stream>>>(yb, wprojT, (void*)out, 8192, 1024, 1024);
}

// Round 3
// 273.915 us; speedup vs baseline: 2.1032x; 2.1032x over previous
//
#include <hip/hip_runtime.h>
#include <hip/hip_bf16.h>

typedef __bf16 bf16x8 __attribute__((ext_vector_type(8)));
typedef __bf16 bf16x4 __attribute__((ext_vector_type(4)));
typedef float  f32x4  __attribute__((ext_vector_type(4)));

#define MFMA16(a,b,c) __builtin_amdgcn_mfma_f32_16x16x32_bf16((a),(b),(c),0,0,0)

#define T_SEQ 2048
#define CDIM  1024
#define NH    16
#define DH    64
#define C3    3072

// async global->LDS, 16B per lane; LDS dest must be wave-uniform base + lane*16
#define GLDS(g, l) __builtin_amdgcn_global_load_lds( \
    (const __attribute__((address_space(1))) void*)(g), \
    (__attribute__((address_space(3))) void*)(l), 16, 0, 0)

// ---------------- cast f32 -> bf16, vectorized ----------------
__global__ void cast_f32_bf16_kernel(const float* __restrict__ in,
                                     __bf16* __restrict__ out, int n4) {
  int i = blockIdx.x * 256 + threadIdx.x;
  if (i >= n4) return;
  f32x4 v = ((const f32x4*)in)[i];
  bf16x4 o;
  o[0] = (__bf16)v[0]; o[1] = (__bf16)v[1];
  o[2] = (__bf16)v[2]; o[3] = (__bf16)v[3];
  ((bf16x4*)out)[i] = o;
}

// ---------------- transpose + cast: W[R][C] f32 -> WT[C][R] bf16 ----------------
__global__ void transpose_cast_kernel(const float* __restrict__ W,
                                      __bf16* __restrict__ WT, int R, int C) {
  __shared__ float tile[32][33];
  int c0 = blockIdx.x * 32, r0 = blockIdx.y * 32;
  int tx = threadIdx.x, ty = threadIdx.y;
#pragma unroll
  for (int i = 0; i < 32; i += 8)
    tile[ty + i][tx] = W[(size_t)(r0 + ty + i) * C + c0 + tx];
  __syncthreads();
#pragma unroll
  for (int i = 0; i < 32; i += 8)
    WT[(size_t)(c0 + ty + i) * R + r0 + tx] = (__bf16)tile[tx][ty + i];
}

// ---------------- transpose V section of qkv -> VT[b][c][t] bf16 ----------------
__global__ void transpose_v_kernel(const __bf16* __restrict__ qkv,
                                   __bf16* __restrict__ VT) {
  __shared__ __bf16 tile[32][33];
  int b  = blockIdx.z;
  int t0 = blockIdx.x * 32;
  int c0 = blockIdx.y * 32;
  int tx = threadIdx.x, ty = threadIdx.y;
#pragma unroll
  for (int i = 0; i < 32; i += 8)
    tile[ty + i][tx] = qkv[(size_t)(b * T_SEQ + t0 + ty + i) * C3 + 2 * CDIM + c0 + tx];
  __syncthreads();
#pragma unroll
  for (int i = 0; i < 32; i += 8)
    VT[((size_t)b * CDIM + c0 + ty + i) * T_SEQ + t0 + tx] = tile[tx][ty + i];
}

// ---------------- bf16 GEMM: C[M][N] = A[M][K] * BT[N][K]^T ----------------
template <int STORE_BF16>
__global__ __launch_bounds__(256)
void gemm_bt_kernel(const __bf16* __restrict__ A, const __bf16* __restrict__ BT,
                    void* __restrict__ Cout, int M, int N, int K) {
  __shared__ __align__(16) __bf16 Alds[128 * 64];
  __shared__ __align__(16) __bf16 Blds[128 * 64];
  const int tid  = threadIdx.x;
  const int lane = tid & 63;
  const int g    = lane >> 4;
  const int l16  = lane & 15;
  const int wave = tid >> 6;
  const int wm   = wave >> 1, wn = wave & 1;
  const int bm   = blockIdx.x, bn = blockIdx.y;

  f32x4 acc[4][4] = {};

  const int soff = tid * 16;
  for (int k0 = 0; k0 < K; k0 += 64) {
    __syncthreads();
#pragma unroll
    for (int c = 0; c < 4; ++c) {
      int off  = c * 4096 + soff;
      int row  = off >> 7;
      int col  = (off & 127) >> 1;
      GLDS(A  + (size_t)(bm * 128 + row) * K + k0 + col, (char*)Alds + off);
      GLDS(BT + (size_t)(bn * 128 + row) * K + k0 + col, (char*)Blds + off);
    }
    __syncthreads();
#pragma unroll
    for (int kk = 0; kk < 2; ++kk) {
      bf16x8 af[4], bf_[4];
#pragma unroll
      for (int i = 0; i < 4; ++i) {
        af[i]  = *(const bf16x8*)&Alds[(wm * 64 + i * 16 + l16) * 64 + kk * 32 + g * 8];
        bf_[i] = *(const bf16x8*)&Blds[(wn * 64 + i * 16 + l16) * 64 + kk * 32 + g * 8];
      }
#pragma unroll
      for (int i = 0; i < 4; ++i)
#pragma unroll
        for (int j = 0; j < 4; ++j)
          acc[i][j] = MFMA16(af[i], bf_[j], acc[i][j]);
    }
  }

#pragma unroll
  for (int i = 0; i < 4; ++i) {
    int crow0 = bm * 128 + wm * 64 + i * 16 + g * 4;
#pragma unroll
    for (int j = 0; j < 4; ++j) {
      int ccol = bn * 128 + wn * 64 + j * 16 + l16;
#pragma unroll
      for (int r = 0; r < 4; ++r) {
        size_t idx = (size_t)(crow0 + r) * N + ccol;
        if (STORE_BF16) ((__bf16*)Cout)[idx] = (__bf16)acc[i][j][r];
        else            ((float*)Cout)[idx]  = acc[i][j][r];
      }
    }
  }
}

// ---------------- causal flash attention, balanced-pair blocks ----------------
// Block = (b, h, pair p): processes qtile p then qtile 31-p  => constant 33
// KV-blocks of 64 per block. 4 waves x 16 q-rows. K staged in LDS (dbuf,
// XOR-swizzled source), V from global VT (reg-prefetched), P via padded LDS.
__global__ __launch_bounds__(256)
void attn_kernel(const __bf16* __restrict__ qkv, const __bf16* __restrict__ VT,
                 __bf16* __restrict__ y) {
  __shared__ __align__(16) __bf16 Klds[2][64 * 64];   // 8KB each, swizzled
  __shared__ __align__(16) __bf16 Plds[4][16][72];    // 144B rows (padded)
  const int tid  = threadIdx.x;
  const int lane = tid & 63;
  const int g    = lane >> 4;
  const int l16  = lane & 15;
  const int wave = tid >> 6;

  const int pairid = blockIdx.x & 15;
  const int bh     = blockIdx.x >> 4;
  const int h      = bh & (NH - 1);
  const int b      = bh >> 4;

  const __bf16* Qg = qkv + (size_t)b * T_SEQ * C3 + h * DH;
  const __bf16* Kg = Qg + CDIM;
  const __bf16* Vt = VT + ((size_t)b * CDIM + h * DH) * T_SEQ;

  // staging map: thread -> (row 0..31 [+32], swizzled col byte)
  const int srow = tid >> 3;
  const int scol = ((tid & 7) * 16) ^ ((srow & 7) << 4);
  const int swz  = (l16 & 7) << 4;   // read-side XOR (row&7)<<4, st*16 keeps row&7=l16&7

  const float SC  = 0.125f * 1.44269504088896340736f;  // scale * log2(e)
  const float THR = 44.4f;                              // raw-domain defer-max thr (2^8 cap)
  const float NEG = -3.0e38f;

#pragma unroll 1
  for (int ph = 0; ph < 2; ++ph) {
    const int qt   = ph ? (31 - pairid) : pairid;
    const int qg0w = qt * 64 + wave * 16;
    const int qrow = qg0w + l16;
    const int qloc = wave * 16 + l16;   // row index within the 64-q tile

    bf16x8 qf[2];
#pragma unroll
    for (int kk = 0; kk < 2; ++kk)
      qf[kk] = *(const bf16x8*)(Qg + (size_t)qrow * C3 + kk * 32 + g * 8);

    float m = NEG, lsum = 0.f;
    f32x4 o[4] = {};

    const int nkb = qt + 1;
    // prologue stage kb=0 into buf0 (prev phase's readers already barriered)
    {
      const __bf16* src = Kg + (size_t)srow * C3 + (scol >> 1);
      GLDS(src, (char*)&Klds[0][0] + tid * 16);
      GLDS(src + (size_t)32 * C3, (char*)&Klds[0][0] + 4096 + tid * 16);
    }
    __syncthreads();

#pragma unroll 1
    for (int kb = 0; kb < nkb; ++kb) {
      const int cur = kb & 1;
      const int kv0 = kb * 64;
      if (kb + 1 < nkb) {   // prefetch next K tile into other buffer
        const __bf16* src = Kg + (size_t)(kv0 + 64 + srow) * C3 + (scol >> 1);
        GLDS(src, (char*)&Klds[cur ^ 1][0] + tid * 16);
        GLDS(src + (size_t)32 * C3, (char*)&Klds[cur ^ 1][0] + 4096 + tid * 16);
      }
      // V prefetch (first half) into regs — latency hidden under QK+softmax
      bf16x8 vf[4][2];
#pragma unroll
      for (int dt = 0; dt < 2; ++dt)
#pragma unroll
        for (int hf = 0; hf < 2; ++hf)
          vf[dt][hf] = *(const bf16x8*)(Vt + (size_t)(dt * 16 + l16) * T_SEQ + kv0 + hf * 32 + g * 8);

      // QK^T: S^T[kv][q], 4 sub-tiles of 16 kv
      f32x4 s[4] = {};
      const char* Kb = (const char*)&Klds[cur][0];
#pragma unroll
      for (int st = 0; st < 4; ++st) {
        const char* rowp = Kb + (st * 16 + l16) * 128;
#pragma unroll
        for (int kk = 0; kk < 2; ++kk) {
          bf16x8 kf = *(const bf16x8*)(rowp + ((kk * 64 + g * 16) ^ swz));
          s[st] = MFMA16(kf, qf[kk], s[st]);
        }
      }
      // V prefetch (second half)
#pragma unroll
      for (int dt = 2; dt < 4; ++dt)
#pragma unroll
        for (int hf = 0; hf < 2; ++hf)
          vf[dt][hf] = *(const bf16x8*)(Vt + (size_t)(dt * 16 + l16) * T_SEQ + kv0 + hf * 32 + g * 8);

      // causal mask: only the diagonal KV-block (block-uniform branch)
      if (kb == qt) {
#pragma unroll
        for (int st = 0; st < 4; ++st)
#pragma unroll
          for (int r = 0; r < 4; ++r)
            if (st * 16 + g * 4 + r > qloc) s[st][r] = NEG;
      }
      // row max (16 vals + cross-g shuffles)
      float tmax = s[0][0];
#pragma unroll
      for (int st = 0; st < 4; ++st)
#pragma unroll
        for (int r = 0; r < 4; ++r) tmax = fmaxf(tmax, s[st][r]);
      tmax = fmaxf(tmax, __shfl_xor(tmax, 16));
      tmax = fmaxf(tmax, __shfl_xor(tmax, 32));

      if (!__all(tmax <= m + THR)) {   // defer-max: rescale only on real growth
        float mnew  = fmaxf(m, tmax);
        float alpha = exp2f((m - mnew) * SC);
        lsum *= alpha;
#pragma unroll
        for (int dt = 0; dt < 4; ++dt) o[dt] *= alpha;
        m = mnew;
      }
      const float msc = m * SC;
      float ls = 0.f;
#pragma unroll
      for (int st = 0; st < 4; ++st) {
        bf16x4 pb;
#pragma unroll
        for (int r = 0; r < 4; ++r) {
          float p = exp2f(__builtin_fmaf(s[st][r], SC, -msc));
          ls += p;
          pb[r] = (__bf16)p;
        }
        *(bf16x4*)((char*)&Plds[wave][l16][0] + st * 32 + g * 8) = pb;
      }
      ls += __shfl_xor(ls, 16);
      ls += __shfl_xor(ls, 32);
      lsum += ls;

      // PV: O^T[d][q] += V^T[d][kv] * P^T[kv][q]
#pragma unroll
      for (int hf = 0; hf < 2; ++hf) {
        bf16x8 pf = *(const bf16x8*)((char*)&Plds[wave][l16][0] + hf * 64 + g * 16);
#pragma unroll
        for (int dt = 0; dt < 4; ++dt)
          o[dt] = MFMA16(vf[dt][hf], pf, o[dt]);
      }
      __syncthreads();   // drains prefetch vmcnt; fences buffer swap
    }

    float inv_l = 1.0f / lsum;
#pragma unroll
    for (int dt = 0; dt < 4; ++dt)
#pragma unroll
      for (int r = 0; r < 4; ++r)
        y[((size_t)b * T_SEQ + qrow) * CDIM + h * DH + dt * 16 + g * 4 + r] =
            (__bf16)(o[dt][r] * inv_l);
  }
}

// ---------------- launch ----------------
extern "C" void kernel_launch(void* const* d_in, const int* in_sizes, int n_in,
                              void* d_out, int out_size, void* d_ws, size_t ws_size,
                              hipStream_t stream) {
  const float* x      = (const float*)d_in[0];   // [4,2048,1024]
  const float* w_qkv  = (const float*)d_in[1];   // [1024,3072]
  const float* w_proj = (const float*)d_in[2];   // [1024,1024]
  float* out = (float*)d_out;                    // [4,2048,1024]

  __bf16* xb     = (__bf16*)d_ws;                // 8192*1024 (reused as VT after GEMM1)
  __bf16* wqkvT  = xb + 8388608;                 // 3072*1024
  __bf16* wprojT = wqkvT + 3145728;              // 1024*1024
  __bf16* qkv    = wprojT + 1048576;             // 8192*3072
  __bf16* yb     = qkv + 25165824;               // 8192*1024
  __bf16* VT     = xb;                           // alias: xb dead after GEMM1

  cast_f32_bf16_kernel<<<8192, 256, 0, stream>>>(x, xb, 2097152);
  transpose_cast_kernel<<<dim3(96, 32), dim3(32, 8), 0, stream>>>(w_qkv, wqkvT, 1024, 3072);
  transpose_cast_kernel<<<dim3(32, 32), dim3(32, 8), 0, stream>>>(w_proj, wprojT, 1024, 1024);
  gemm_bt_kernel<1><<<dim3(64, 24), 256, 0, stream>>>(xb, wqkvT, (void*)qkv, 8192, 3072, 1024);
  transpose_v_kernel<<<dim3(64, 32, 4), dim3(32, 8), 0, stream>>>(qkv, VT);
  attn_kernel<<<1024, 256, 0, stream>>>(qkv, VT, yb);
  gemm_bt_kernel<0><<<dim3(64, 8), 256, 0, stream>>>(yb, wprojT, (void*)out, 8192, 1024, 1024);
}